// Round 4
// baseline (171.154 us; speedup 1.0000x reference)
//
#include <hip/hip_runtime.h>

// RickerCWT via bf16 MFMA GEMM (round 8): out[b,s,t] = sum_k x[b,t+k-271]*W[s,k]
// - Pre-kernel repacks W fp32 -> bf16 in MFMA-fragment order (wconv), so a
//   wave's B-fragment pair for K-step ks is one contiguous 2KB block.
// - B-fragments staged global->LDS via async global_load_lds, 3-deep pipeline,
//   counted s_waitcnt vmcnt(6/4/2/0) (T3/T4). FIX vs round 7: staging buffers
//   are PER-WAVE PRIVATE (wsm[wv][4][1024]) -- round 7 shared one ring across
//   free-running waves, so a fast wave's STAGE(ks+3) clobbered a slow wave's
//   current stage (absmax 238). With private rings each wave's own vmcnt is a
//   complete ordering; no K-loop barriers needed. Redundant 4x staging reads
//   are L1-resident (same traffic round 6 paid via direct global B reads).
// - Phase B staging vectorized: 2 ds_read_b128 + 8 ds_write_b128 per active
//   thread (shift c compile-time), replacing 66 scalar u16 LDS ops.
// - Wave tile 128t x 64s (4x2 frags, mfma_f32_32x32x16_bf16), block = 4
//   waves, grid 8x128. s_setprio(1) around the MFMA cluster (T5).
// - LDS: xraw 2.1KB + xsm 16.8KB + wsm 32KB = 51.6KB; 2 blocks/CU -> 103KB,
//   still VGPR-limited (not LDS-limited) at 2 waves/SIMD.

#define TLEN  4096
#define NSC   64
#define KLEN  543
#define KPAD  544            // 34 * 16
#define PADL  271
#define BLOCK 256
#define TT    512            // t per block (4 waves x 128t)
#define XSRC  1056           // raw staged x elems (132 short8)
#define XLEN  1048           // per-copy slots
#define XREG  1048           // copy stride in elems (131*8, odd chunk stride)
#define NKS   34             // K-steps of 16

typedef __attribute__((ext_vector_type(8)))  short  short8;
typedef __attribute__((ext_vector_type(16))) float  float16v;
typedef __attribute__((ext_vector_type(4)))  float  float4v;

__device__ __forceinline__ ushort f2bf(float f) {
    unsigned u = __builtin_bit_cast(unsigned, f);
    unsigned r = (u + 0x7FFFu + ((u >> 16) & 1u)) >> 16;
    return (ushort)r;
}

__global__ __launch_bounds__(256)
void wconv(const float* __restrict__ W, ushort* __restrict__ wpk)
{
    int idx  = blockIdx.x * 256 + threadIdx.x;    // 0..34815
    int e    = idx & 7;                           // elem within lane's 16B
    int lane = (idx >> 3) & 63;                   // hw lane order
    int st   = (idx >> 9) & 1;                    // s-frag (0: s<32, 1: s>=32)
    int ks   = idx >> 10;                         // K-step of 16
    int n    = lane & 31;
    int q5   = lane >> 5;
    int s    = 32 * st + n;
    int k    = 16 * ks + 8 * q5 + e;
    float v  = (k < KLEN) ? W[(size_t)s * KLEN + k] : 0.0f;
    wpk[idx] = f2bf(v);
}

__global__ __launch_bounds__(BLOCK, 2)
void ricker_mfma2(const float* __restrict__ x,
                  const ushort* __restrict__ wpk,
                  float* __restrict__ out)
{
    __shared__ __align__(16) ushort xraw[XSRC];
    __shared__ __align__(16) ushort xsm[8 * XREG];      // 16768 B
    __shared__ __align__(16) ushort wsm[4][4][1024];    // 32768 B, per-wave rings

    const int tid    = threadIdx.x;
    const int tTile  = blockIdx.x;        // 0..7
    const int b      = blockIdx.y;        // 0..127
    const int tStart = tTile * TT;

    // ---- phase A: raw bf16 x tile (halo, zero-padded), coalesced ----
    const float* xrow = x + (size_t)b * TLEN;
    for (int i = tid; i < XSRC; i += BLOCK) {
        int g = tStart - PADL + i;
        float v = (g >= 0 && g < TLEN) ? xrow[g] : 0.0f;
        xraw[i] = f2bf(v);
    }
    __syncthreads();

    // ---- phase B: 8 shifted copies, vectorized b128 (shift c compile-time) --
    {
        const short8* xr8 = (const short8*)xraw;
        short8*       xs8 = (short8*)xsm;
        for (int j = tid; j < 131; j += BLOCK) {      // one predicated pass
            short8 lo = xr8[j];
            short8 hi = xr8[j + 1];
            #pragma unroll
            for (int c = 0; c < 8; ++c) {
                short8 r;
                #pragma unroll
                for (int e = 0; e < 8; ++e)
                    r[e] = (c + e < 8) ? lo[c + e] : hi[c + e - 8];
                xs8[c * 131 + j] = r;                 // == xsm[c*XREG + 8j]
            }
        }
    }
    __syncthreads();

    // ---- wave GEMM: 128t x 64s, mfma_f32_32x32x16_bf16, 4x2 frags ----
    const int lane = tid & 63;
    const int wv   = tid >> 6;        // 0..3
    const int n    = lane & 31;       // A row m / B col n / D col (s)
    const int q5   = lane >> 5;       // k-half
    const int wt0  = wv * 128;

    // A element = wt0 + 32*tt + m + k, k = 16*ks + 8*q5 + j; copy c = m&7,
    // slot = wt0 + 32*tt + 8*(m>>3) + 16*ks + 8*q5 (multiple of 8).
    const ushort* abase = &xsm[(n & 7) * XREG + 8 * (n >> 3) + 8 * q5 + wt0];
    // B stage source: lane l reads wpk[1024*ks + 8*l (+512)], lands at
    // wsm[wv][ks&3][8*l (+512)] -- exactly the bytes lane l consumes.
    const ushort* bglob = wpk + (size_t)lane * 8;

    float16v acc[4][2];
    #pragma unroll
    for (int tt = 0; tt < 4; ++tt)
        #pragma unroll
        for (int st = 0; st < 2; ++st)
            #pragma unroll
            for (int e = 0; e < 16; ++e) acc[tt][st][e] = 0.f;

#define STAGE(kss) do {                                                          \
        const ushort* g0_ = bglob + 1024 * (kss);                                \
        __builtin_amdgcn_global_load_lds(                                        \
            (const __attribute__((address_space(1))) void*)g0_,                  \
            (__attribute__((address_space(3))) void*)&wsm[wv][(kss) & 3][0],     \
            16, 0, 0);                                                           \
        __builtin_amdgcn_global_load_lds(                                        \
            (const __attribute__((address_space(1))) void*)(g0_ + 512),          \
            (__attribute__((address_space(3))) void*)&wsm[wv][(kss) & 3][512],   \
            16, 0, 0);                                                           \
    } while (0)

#define KSTEP(kss, WAITASM) do {                                                 \
        asm volatile(WAITASM ::: "memory");                                      \
        __builtin_amdgcn_sched_barrier(0);                                       \
        const ushort* wrow_ = &wsm[wv][(kss) & 3][0];                            \
        short8 bb0 = *(const short8*)&wrow_[lane * 8];                           \
        short8 bb1 = *(const short8*)&wrow_[512 + lane * 8];                     \
        const int K0_ = 16 * (kss);                                              \
        short8 a0 = *(const short8*)&abase[K0_];                                 \
        short8 a1 = *(const short8*)&abase[K0_ + 32];                            \
        short8 a2 = *(const short8*)&abase[K0_ + 64];                            \
        short8 a3 = *(const short8*)&abase[K0_ + 96];                            \
        __builtin_amdgcn_s_setprio(1);                                           \
        acc[0][0] = __builtin_amdgcn_mfma_f32_32x32x16_bf16(a0, bb0, acc[0][0], 0, 0, 0); \
        acc[0][1] = __builtin_amdgcn_mfma_f32_32x32x16_bf16(a0, bb1, acc[0][1], 0, 0, 0); \
        acc[1][0] = __builtin_amdgcn_mfma_f32_32x32x16_bf16(a1, bb0, acc[1][0], 0, 0, 0); \
        acc[1][1] = __builtin_amdgcn_mfma_f32_32x32x16_bf16(a1, bb1, acc[1][1], 0, 0, 0); \
        acc[2][0] = __builtin_amdgcn_mfma_f32_32x32x16_bf16(a2, bb0, acc[2][0], 0, 0, 0); \
        acc[2][1] = __builtin_amdgcn_mfma_f32_32x32x16_bf16(a2, bb1, acc[2][1], 0, 0, 0); \
        acc[3][0] = __builtin_amdgcn_mfma_f32_32x32x16_bf16(a3, bb0, acc[3][0], 0, 0, 0); \
        acc[3][1] = __builtin_amdgcn_mfma_f32_32x32x16_bf16(a3, bb1, acc[3][1], 0, 0, 0); \
        __builtin_amdgcn_s_setprio(0);                                           \
    } while (0)

    // prologue: fill 3 stages (6 loads in flight, all this wave's own)
    STAGE(0); STAGE(1); STAGE(2);

    // steady state: issue stage ks+3, wait until stage ks landed (<=6 behind)
    for (int ks = 0; ks < NKS - 3; ++ks) {
        STAGE(ks + 3);
        KSTEP(ks, "s_waitcnt vmcnt(6)");
    }
    // drain
    KSTEP(NKS - 3, "s_waitcnt vmcnt(4)");
    KSTEP(NKS - 2, "s_waitcnt vmcnt(2)");
    KSTEP(NKS - 1, "s_waitcnt vmcnt(0)");

#undef STAGE
#undef KSTEP

    // ---- epilogue: D col = n (s), row = (reg&3) + 8*(reg>>2) + 4*q5 (t) ----
    const int tb = tStart + wt0 + 4 * q5;
    float* obase = out + (size_t)b * NSC * TLEN;
    #pragma unroll
    for (int st = 0; st < 2; ++st) {
        #pragma unroll
        for (int tt = 0; tt < 4; ++tt) {
            float16v A = acc[tt][st];
            float* o = obase + (size_t)(32 * st + n) * TLEN + tb + 32 * tt;
            #pragma unroll
            for (int r4 = 0; r4 < 4; ++r4) {
                *(float4v*)&o[8 * r4] =
                    (float4v){A[4 * r4], A[4 * r4 + 1], A[4 * r4 + 2], A[4 * r4 + 3]};
            }
        }
    }
}

extern "C" void kernel_launch(void* const* d_in, const int* in_sizes, int n_in,
                              void* d_out, int out_size, void* d_ws, size_t ws_size,
                              hipStream_t stream) {
    const float* x   = (const float*)d_in[0];   // [128, 4096] fp32
    const float* W   = (const float*)d_in[1];   // [64, 543]  fp32
    float*       out = (float*)d_out;           // [128, 64, 4096] fp32
    ushort*      wpk = (ushort*)d_ws;           // [34,2,64,8] bf16 blocks (69,632 B)

    wconv<<<dim3((NSC * KPAD) / 256), dim3(256), 0, stream>>>(W, wpk);
    dim3 grid(TLEN / TT, 128);                  // (8, 128) = 1024 blocks
    ricker_mfma2<<<grid, dim3(BLOCK), 0, stream>>>(x, wpk, out);
}

// Round 5
// 171.122 us; speedup vs baseline: 1.0002x; 1.0002x over previous
//
#include <hip/hip_runtime.h>

// RickerCWT via bf16 MFMA GEMM (round 9): out[b,s,t] = sum_k x[b,t+k-271]*W[s,k]
// - Pre-kernel repacks W fp32 -> bf16 in MFMA-fragment order (wconv): each
//   wave B-fragment load is one fully-coalesced aligned 1KB segment.
// - K-loop: DIRECT global B-frag loads (r6 structure — proven best; async
//   LDS staging of B regressed +6us in r8: 4x VMEM instrs + LDS round-trip).
// - NEW vs r6: __launch_bounds__(256,3) forces VGPR<=170 so the 4x2-frag
//   tile runs at 3 waves/SIMD (r6 ran 2). Theory: kernel is overlap-bound
//   (store burst + staging exposed between K-loops); +50% TLP hides it.
// - Wave tile 128t x 64s (4x2 frags, mfma_f32_32x32x16_bf16), block = 4
//   waves, grid 8x128 = 1024 blocks.
// - A (sliding x window) from LDS via 8 one-element-shifted copies, stride
//   1048 elems (131*8, odd 16B-chunk) keeps ds_read_b128 bank-balanced.
//   Phase B staging vectorized: 2 ds_read_b128 + 8 ds_write_b128 per thread.
// - LDS: xraw 2.1KB + xsm 16.8KB = 18.9KB; 3 blocks/CU -> 57KB, fine.

#define TLEN  4096
#define NSC   64
#define KLEN  543
#define KPAD  544            // 34 * 16
#define PADL  271
#define BLOCK 256
#define TT    512            // t per block (4 waves x 128t)
#define XSRC  1056           // raw staged x elems (132 short8)
#define XLEN  1048           // per-copy slots
#define XREG  1048           // copy stride in elems (131*8, odd chunk stride)
#define NKS   34             // K-steps of 16

typedef __attribute__((ext_vector_type(8)))  short  short8;
typedef __attribute__((ext_vector_type(16))) float  float16v;
typedef __attribute__((ext_vector_type(4)))  float  float4v;

__device__ __forceinline__ ushort f2bf(float f) {
    unsigned u = __builtin_bit_cast(unsigned, f);
    unsigned r = (u + 0x7FFFu + ((u >> 16) & 1u)) >> 16;
    return (ushort)r;
}

__global__ __launch_bounds__(256)
void wconv(const float* __restrict__ W, ushort* __restrict__ wpk)
{
    int idx  = blockIdx.x * 256 + threadIdx.x;    // 0..34815
    int e    = idx & 7;                           // elem within lane's 16B
    int lane = (idx >> 3) & 63;                   // hw lane order
    int st   = (idx >> 9) & 1;                    // s-frag (0: s<32, 1: s>=32)
    int ks   = idx >> 10;                         // K-step of 16
    int n    = lane & 31;
    int q5   = lane >> 5;
    int s    = 32 * st + n;
    int k    = 16 * ks + 8 * q5 + e;
    float v  = (k < KLEN) ? W[(size_t)s * KLEN + k] : 0.0f;
    wpk[idx] = f2bf(v);
}

__global__ __launch_bounds__(BLOCK, 3)
void ricker_mfma2(const float* __restrict__ x,
                  const ushort* __restrict__ wpk,
                  float* __restrict__ out)
{
    __shared__ __align__(16) ushort xraw[XSRC];
    __shared__ __align__(16) ushort xsm[8 * XREG];   // 16768 B

    const int tid    = threadIdx.x;
    const int tTile  = blockIdx.x;        // 0..7
    const int b      = blockIdx.y;        // 0..127
    const int tStart = tTile * TT;

    // ---- phase A: raw bf16 x tile (halo, zero-padded), coalesced ----
    const float* xrow = x + (size_t)b * TLEN;
    for (int i = tid; i < XSRC; i += BLOCK) {
        int g = tStart - PADL + i;
        float v = (g >= 0 && g < TLEN) ? xrow[g] : 0.0f;
        xraw[i] = f2bf(v);
    }
    __syncthreads();

    // ---- phase B: 8 shifted copies, vectorized b128 (shift c compile-time) --
    {
        const short8* xr8 = (const short8*)xraw;
        short8*       xs8 = (short8*)xsm;
        for (int j = tid; j < 131; j += BLOCK) {      // one predicated pass
            short8 lo = xr8[j];
            short8 hi = xr8[j + 1];
            #pragma unroll
            for (int c = 0; c < 8; ++c) {
                short8 r;
                #pragma unroll
                for (int e = 0; e < 8; ++e)
                    r[e] = (c + e < 8) ? lo[c + e] : hi[c + e - 8];
                xs8[c * 131 + j] = r;                 // == xsm[c*XREG + 8j]
            }
        }
    }
    __syncthreads();

    // ---- wave GEMM: 128t x 64s, mfma_f32_32x32x16_bf16, 4x2 frags ----
    const int lane = tid & 63;
    const int wv   = tid >> 6;        // 0..3
    const int n    = lane & 31;       // A row m / B col n / D col (s)
    const int q5   = lane >> 5;       // k-half
    const int wt0  = wv * 128;

    // A element = wt0 + 32*tt + m + k, k = 16*ks + 8*q5 + j; copy c = m&7,
    // slot = wt0 + 32*tt + 8*(m>>3) + 16*ks + 8*q5 (multiple of 8).
    const ushort* abase = &xsm[(n & 7) * XREG + 8 * (n >> 3) + 8 * q5 + wt0];
    // B-frag: per-(ks,st) 1KB block, lane-ordered -> fully coalesced 16B/lane.
    const ushort* bbase = wpk + (size_t)lane * 8;

    float16v acc[4][2];
    #pragma unroll
    for (int tt = 0; tt < 4; ++tt)
        #pragma unroll
        for (int st = 0; st < 2; ++st)
            #pragma unroll
            for (int e = 0; e < 16; ++e) acc[tt][st][e] = 0.f;

    #pragma unroll 2
    for (int ks = 0; ks < NKS; ++ks) {
        const int K0 = 16 * ks;
        const int BO = 1024 * ks;                        // (ks*2)*512 elems
        short8 bb0 = *(const short8*)&bbase[BO];         // st=0
        short8 bb1 = *(const short8*)&bbase[BO + 512];   // st=1
        short8 a[4];
        #pragma unroll
        for (int tt = 0; tt < 4; ++tt)
            a[tt] = *(const short8*)&abase[K0 + 32 * tt];
        __builtin_amdgcn_s_setprio(1);
        #pragma unroll
        for (int tt = 0; tt < 4; ++tt) {
            acc[tt][0] = __builtin_amdgcn_mfma_f32_32x32x16_bf16(a[tt], bb0, acc[tt][0], 0, 0, 0);
            acc[tt][1] = __builtin_amdgcn_mfma_f32_32x32x16_bf16(a[tt], bb1, acc[tt][1], 0, 0, 0);
        }
        __builtin_amdgcn_s_setprio(0);
    }

    // ---- epilogue: D col = n (s), row = (reg&3) + 8*(reg>>2) + 4*q5 (t) ----
    const int tb = tStart + wt0 + 4 * q5;
    float* obase = out + (size_t)b * NSC * TLEN;
    #pragma unroll
    for (int st = 0; st < 2; ++st) {
        #pragma unroll
        for (int tt = 0; tt < 4; ++tt) {
            float16v A = acc[tt][st];
            float* o = obase + (size_t)(32 * st + n) * TLEN + tb + 32 * tt;
            #pragma unroll
            for (int r4 = 0; r4 < 4; ++r4) {
                *(float4v*)&o[8 * r4] =
                    (float4v){A[4 * r4], A[4 * r4 + 1], A[4 * r4 + 2], A[4 * r4 + 3]};
            }
        }
    }
}

extern "C" void kernel_launch(void* const* d_in, const int* in_sizes, int n_in,
                              void* d_out, int out_size, void* d_ws, size_t ws_size,
                              hipStream_t stream) {
    const float* x   = (const float*)d_in[0];   // [128, 4096] fp32
    const float* W   = (const float*)d_in[1];   // [64, 543]  fp32
    float*       out = (float*)d_out;           // [128, 64, 4096] fp32
    ushort*      wpk = (ushort*)d_ws;           // [34,2,64,8] bf16 blocks (69,632 B)

    wconv<<<dim3((NSC * KPAD) / 256), dim3(256), 0, stream>>>(W, wpk);
    dim3 grid(TLEN / TT, 128);                  // (8, 128) = 1024 blocks
    ricker_mfma2<<<grid, dim3(BLOCK), 0, stream>>>(x, wpk, out);
}

// Round 6
// 153.442 us; speedup vs baseline: 1.1154x; 1.1152x over previous
//
#include <hip/hip_runtime.h>

// RickerCWT via f16 MFMA GEMM, symmetry-halved K (round 10):
//   out[b,s,t] = sum_k x[b,t+k-271]*W[s,k],  W even-symmetric about k=271
//             = sum_{d=0..271} W'[s,d] * z[t,d],
//   z[t,d] = x[t+d] + x[t-d],  W'[s,d] = W[s,271+d],  W'[s,0] halved.
// K: 543 -> 272 = 17 MFMA K-steps (was 34): MFMA work, B traffic and K-loop
// iteration count all halve. f16 (not bf16) so z is built with v_pk_add_f16;
// f16's 10-bit mantissa is MORE accurate than the passing bf16 path.
// - z-frag construction: forward slab aligned ds_read_b128 (Hankel, same
//   8-shifted-copy LDS trick as before) + backward slab aligned ds_read_b128
//   + 8-elem reversal (4 v_alignbit) + 4 v_pk_add_f16.
// - Pre-kernel packs W' f16 in MFMA-fragment order: each wave B-frag load is
//   one coalesced aligned 1KB segment, read DIRECT from global (L1-resident;
//   async LDS staging of B regressed in r8).
// - Wave tile 128t x 64s (4x2 frags, mfma_f32_32x32x16_f16), block = 4 waves,
//   grid 8x128 = 1024 blocks, lb(256,2) (lb3 spilled in r9: +6us).
// - LDS: xraw 2.1KB + xsm 16.8KB = 18.9KB.

#define TLEN  4096
#define NSC   64
#define KLEN  543
#define PADL  271
#define BLOCK 256
#define TT    512            // t per block (4 waves x 128t)
#define XSRC  1056           // raw staged x elems (132 short8)
#define XLEN  1048           // per-copy slots
#define XREG  1048           // copy stride in elems (131*8, odd chunk stride)
#define NKS2  17             // K-steps of 16 over d=0..271
#define WPK_N (NKS2 * 2 * 64 * 8)   // 17408 f16 elems

typedef __attribute__((ext_vector_type(8)))  short     short8;
typedef __attribute__((ext_vector_type(8)))  _Float16  half8;
typedef __attribute__((ext_vector_type(16))) float     float16v;
typedef __attribute__((ext_vector_type(4)))  float     float4v;

__global__ __launch_bounds__(256)
void wconv(const float* __restrict__ W, _Float16* __restrict__ wpk)
{
    int idx  = blockIdx.x * 256 + threadIdx.x;    // 0..17407
    int e    = idx & 7;                           // elem within lane's 16B
    int lane = (idx >> 3) & 63;                   // hw lane order
    int st   = (idx >> 9) & 1;                    // s-frag (0: s<32, 1: s>=32)
    int ks   = idx >> 10;                         // K-step of 16 (0..16)
    int n    = lane & 31;
    int q5   = lane >> 5;
    int s    = 32 * st + n;
    int d    = 16 * ks + 8 * q5 + e;              // 0..271
    float v  = W[(size_t)s * KLEN + PADL + d];    // W'[s,d] = W[s,271+d]
    if (d == 0) v *= 0.5f;                        // absorb z[t,0] = 2*x[t]
    wpk[idx] = (_Float16)v;
}

__global__ __launch_bounds__(BLOCK, 2)
void ricker_mfma2(const float* __restrict__ x,
                  const _Float16* __restrict__ wpk,
                  float* __restrict__ out)
{
    __shared__ __align__(16) _Float16 xraw[XSRC];
    __shared__ __align__(16) _Float16 xsm[8 * XREG];   // 16768 B

    const int tid    = threadIdx.x;
    const int tTile  = blockIdx.x;        // 0..7
    const int b      = blockIdx.y;        // 0..127
    const int tStart = tTile * TT;

    // ---- phase A: raw f16 x tile (halo, zero-padded), coalesced ----
    const float* xrow = x + (size_t)b * TLEN;
    for (int i = tid; i < XSRC; i += BLOCK) {
        int g = tStart - PADL + i;
        float v = (g >= 0 && g < TLEN) ? xrow[g] : 0.0f;
        xraw[i] = (_Float16)v;
    }
    __syncthreads();

    // ---- phase B: 8 shifted copies, vectorized b128 (shift c compile-time) --
    // xsm[c*XREG + p] = xraw[p + c], p in [0, XLEN), c in [0,8).
    {
        const short8* xr8 = (const short8*)xraw;
        short8*       xs8 = (short8*)xsm;
        for (int j = tid; j < 131; j += BLOCK) {      // one predicated pass
            short8 lo = xr8[j];
            short8 hi = xr8[j + 1];
            #pragma unroll
            for (int c = 0; c < 8; ++c) {
                short8 r;
                #pragma unroll
                for (int e = 0; e < 8; ++e)
                    r[e] = (c + e < 8) ? lo[c + e] : hi[c + e - 8];
                xs8[c * 131 + j] = r;                 // == xsm[c*XREG + 8j]
            }
        }
    }
    __syncthreads();

    // ---- wave GEMM: 128t x 64s, mfma_f32_32x32x16_f16, 4x2 frags ----
    const int lane = tid & 63;
    const int wv   = tid >> 6;        // 0..3
    const int n    = lane & 31;       // A row m / B col n / D col (s)
    const int q5   = lane >> 5;       // k-half
    const int wt0  = wv * 128;

    // Forward slab: f[j] = x[t+d0+j] = xraw[tau + 271 + d0 + j],
    //   tau = wt0+32tt+n, d0 = 16ks+8q5.  Start S_f = tau+271+d0:
    //   copy cf = (n+7)&7, in-copy slot = wt0+8q5+(n+271-cf) + 16ks+32tt.
    // Backward slab: r[e] = xraw[tau + 264 - d0 + e]  (so rev(r)[j]=x[t-d0-j]):
    //   copy cr = n&7,     in-copy slot = wt0-8q5+264+(n-cr) - 16ks+32tt.
    const int cf = (n + 7) & 7;
    const int cr = n & 7;
    const _Float16* af = &xsm[cf * XREG + wt0 + 8 * q5 + (n + PADL - cf)];
    const _Float16* ar = &xsm[cr * XREG + wt0 - 8 * q5 + 264 + (n - cr)];
    // B-frag: per-(ks,st) 1KB block, lane-ordered -> fully coalesced 16B/lane.
    const _Float16* bbase = wpk + (size_t)lane * 8;

    float16v acc[4][2];
    #pragma unroll
    for (int tt = 0; tt < 4; ++tt)
        #pragma unroll
        for (int st = 0; st < 2; ++st)
            #pragma unroll
            for (int e = 0; e < 16; ++e) acc[tt][st][e] = 0.f;

    #pragma unroll 2
    for (int ks = 0; ks < NKS2; ++ks) {
        const int KF = 16 * ks;
        const int BO = 1024 * ks;                        // (ks*2)*512 elems
        half8 bb0 = *(const half8*)&bbase[BO];           // st=0
        half8 bb1 = *(const half8*)&bbase[BO + 512];     // st=1
        half8 z[4];
        #pragma unroll
        for (int tt = 0; tt < 4; ++tt) {
            half8 f = *(const half8*)&af[KF + 32 * tt];
            half8 r = *(const half8*)&ar[32 * tt - KF];
            half8 rv = __builtin_shufflevector(r, r, 7, 6, 5, 4, 3, 2, 1, 0);
            z[tt] = f + rv;                              // v_pk_add_f16 x4
        }
        #pragma unroll
        for (int tt = 0; tt < 4; ++tt) {
            acc[tt][0] = __builtin_amdgcn_mfma_f32_32x32x16_f16(z[tt], bb0, acc[tt][0], 0, 0, 0);
            acc[tt][1] = __builtin_amdgcn_mfma_f32_32x32x16_f16(z[tt], bb1, acc[tt][1], 0, 0, 0);
        }
    }

    // ---- epilogue: D col = n (s), row = (reg&3) + 8*(reg>>2) + 4*q5 (t) ----
    const int tb = tStart + wt0 + 4 * q5;
    float* obase = out + (size_t)b * NSC * TLEN;
    #pragma unroll
    for (int st = 0; st < 2; ++st) {
        #pragma unroll
        for (int tt = 0; tt < 4; ++tt) {
            float16v A = acc[tt][st];
            float* o = obase + (size_t)(32 * st + n) * TLEN + tb + 32 * tt;
            #pragma unroll
            for (int r4 = 0; r4 < 4; ++r4) {
                *(float4v*)&o[8 * r4] =
                    (float4v){A[4 * r4], A[4 * r4 + 1], A[4 * r4 + 2], A[4 * r4 + 3]};
            }
        }
    }
}

extern "C" void kernel_launch(void* const* d_in, const int* in_sizes, int n_in,
                              void* d_out, int out_size, void* d_ws, size_t ws_size,
                              hipStream_t stream) {
    const float* x   = (const float*)d_in[0];   // [128, 4096] fp32
    const float* W   = (const float*)d_in[1];   // [64, 543]  fp32
    float*       out = (float*)d_out;           // [128, 64, 4096] fp32
    _Float16*    wpk = (_Float16*)d_ws;         // [17,2,64,8] f16 blocks (34,816 B)

    wconv<<<dim3(WPK_N / 256), dim3(256), 0, stream>>>(W, wpk);
    dim3 grid(TLEN / TT, 128);                  // (8, 128) = 1024 blocks
    ricker_mfma2<<<grid, dim3(BLOCK), 0, stream>>>(x, wpk, out);
}